// Round 2
// baseline (369.288 us; speedup 1.0000x reference)
//
#include <hip/hip_runtime.h>
#include <hip/hip_bf16.h>
#include <math.h>

// Problem constants (from reference): B=8, S=4096, D=2048, E=64, TOP_K=2
#define BB 8
#define SS 4096
#define DD 2048
#define EE 64
#define NCHUNK 64                      // S split into 64 chunks
#define ROWS (SS / NCHUNK)             // 64 rows per chunk
#define NSLICE (NCHUNK * 2)            // 128 logit-partial slices per batch

// Kernel 1 (fused): stream x, accumulate column sums for a (b, S-chunk,
// half-D) tile, then dot against the matching W slice to emit 64 partial
// logits. Output: plogit[blk][e], blk = b*128 + c*2 + h.
// grid = BB*NCHUNK*2 = 1024 blocks (4 blocks/CU, 16 waves/CU), 256 threads.
//
// Phase B fix (round 1, unmeasured due to infra failures): the old mapping
// (lane = expert) made every wave-load touch 64 cache lines 8 KB apart
// (fully uncoalesced, ~65K L1 transactions/CU — 4x the entire x-stream).
// New mapping: each wave owns 16 experts sequentially; lanes sweep the
// expert row with float4 loads (1 KB contiguous per instruction), then
// shfl-xor reduce to a scalar.
__global__ void __launch_bounds__(256, 4)
fused_stream_kernel(const float* __restrict__ x,
                    const float* __restrict__ W,
                    float* __restrict__ plogit) {
    __shared__ float xs[DD / 2];     // 4 KB: this block's column sums
    __shared__ float lout[EE];       // 256 B: per-block partial logits

    int blk = blockIdx.x;
    int h   = blk & 1;                    // which half of D
    int c   = (blk >> 1) & (NCHUNK - 1);
    int b   = blk >> 7;                   // 1024/128 = 8 batches
    int tid = threadIdx.x;
    int d   = h * (DD / 2) + tid * 4;

    // Phase A: column sums over ROWS rows (4 independent accumulators).
    // Coalesced: 256 threads x float4 = 4 KB contiguous per row read.
    const float4* xp = (const float4*)(x + (size_t)b * SS * DD
                                         + (size_t)c * ROWS * DD + d);
    float4 a0 = make_float4(0.f, 0.f, 0.f, 0.f);
    float4 a1 = make_float4(0.f, 0.f, 0.f, 0.f);
    float4 a2 = make_float4(0.f, 0.f, 0.f, 0.f);
    float4 a3 = make_float4(0.f, 0.f, 0.f, 0.f);
    const size_t rs = DD / 4;             // float4 row stride
    #pragma unroll 4
    for (int r = 0; r < ROWS; r += 4) {
        float4 v0 = xp[(size_t)(r + 0) * rs];
        float4 v1 = xp[(size_t)(r + 1) * rs];
        float4 v2 = xp[(size_t)(r + 2) * rs];
        float4 v3 = xp[(size_t)(r + 3) * rs];
        a0.x += v0.x; a0.y += v0.y; a0.z += v0.z; a0.w += v0.w;
        a1.x += v1.x; a1.y += v1.y; a1.z += v1.z; a1.w += v1.w;
        a2.x += v2.x; a2.y += v2.y; a2.z += v2.z; a2.w += v2.w;
        a3.x += v3.x; a3.y += v3.y; a3.z += v3.z; a3.w += v3.w;
    }
    float4 acc;
    acc.x = (a0.x + a1.x) + (a2.x + a3.x);
    acc.y = (a0.y + a1.y) + (a2.y + a3.y);
    acc.z = (a0.z + a1.z) + (a2.z + a3.z);
    acc.w = (a0.w + a1.w) + (a2.w + a3.w);
    ((float4*)xs)[tid] = acc;
    __syncthreads();

    // Phase B: wave w -> experts [w*16, w*16+16). Lanes sweep columns
    // (coalesced 1 KB per wave-load), 6-step shfl-xor reduce per expert.
    int wave = tid >> 6;
    int lane = tid & 63;
    const float4* xs4 = (const float4*)xs;    // 256 float4s
    float4 xv0 = xs4[lane +   0];
    float4 xv1 = xs4[lane +  64];
    float4 xv2 = xs4[lane + 128];
    float4 xv3 = xs4[lane + 192];
    const float* Wbase = W + (size_t)(wave * 16) * DD + h * (DD / 2);
    #pragma unroll 4
    for (int j = 0; j < 16; ++j) {
        const float4* wp = (const float4*)(Wbase + (size_t)j * DD) + lane;
        float4 w0 = wp[0];
        float4 w1 = wp[64];
        float4 w2 = wp[128];
        float4 w3 = wp[192];
        float s = (w0.x * xv0.x + w0.y * xv0.y + w0.z * xv0.z + w0.w * xv0.w)
                + (w1.x * xv1.x + w1.y * xv1.y + w1.z * xv1.z + w1.w * xv1.w)
                + (w2.x * xv2.x + w2.y * xv2.y + w2.z * xv2.z + w2.w * xv2.w)
                + (w3.x * xv3.x + w3.y * xv3.y + w3.z * xv3.z + w3.w * xv3.w);
        #pragma unroll
        for (int off = 32; off; off >>= 1)
            s += __shfl_xor(s, off, 64);
        if (lane == 0) lout[wave * 16 + j] = s;
    }
    __syncthreads();

    if (tid < EE) {
        plogit[(size_t)blk * EE + tid] = lout[tid];
    }
}

// Kernel 2: per-batch reduce the 128 logit-partial slices, scale by 1/S,
// add bias, top-2 + softmax. grid = 8 blocks, 256 threads.
__global__ void gate_kernel(const float* __restrict__ plogit,
                            const float* __restrict__ bias,
                            float* __restrict__ out) {
    __shared__ float lred[4][EE];
    __shared__ float logits[EE];

    int b   = blockIdx.x;
    int tid = threadIdx.x;
    int e   = tid & 63;
    int g   = tid >> 6;                   // group of 32 slices

    float s = 0.f;
    #pragma unroll 8
    for (int j = g * (NSLICE / 4); j < (g + 1) * (NSLICE / 4); ++j)
        s += plogit[((size_t)b * NSLICE + j) * EE + e];
    lred[g][e] = s;
    __syncthreads();

    if (tid < EE) {
        logits[tid] = (lred[0][tid] + lred[1][tid] + lred[2][tid] + lred[3][tid])
                      * (1.0f / SS) + bias[tid];
    }
    __syncthreads();

    // top-2 (stable: lowest index wins ties, matching lax.top_k) + softmax
    if (tid == 0) {
        float m1 = -INFINITY, m2 = -INFINITY;
        int i1 = 0, i2 = 0;
        for (int i = 0; i < EE; ++i) {
            float v = logits[i];
            if (v > m1) { m2 = m1; i2 = i1; m1 = v; i1 = i; }
            else if (v > m2) { m2 = v; i2 = i; }
        }
        float e2 = expf(m2 - m1);
        float inv = 1.0f / (1.0f + e2);
        // outputs concatenated flat: weights [8,2] then indices [8,2]
        out[b * 2 + 0] = inv;
        out[b * 2 + 1] = e2 * inv;
        out[2 * BB + b * 2 + 0] = (float)i1;
        out[2 * BB + b * 2 + 1] = (float)i2;
    }
}

extern "C" void kernel_launch(void* const* d_in, const int* in_sizes, int n_in,
                              void* d_out, int out_size, void* d_ws, size_t ws_size,
                              hipStream_t stream) {
    const float* x  = (const float*)d_in[0];   // [8, 4096, 2048]
    const float* W  = (const float*)d_in[1];   // [64, 2048]
    const float* bb = (const float*)d_in[2];   // [64]
    float* out      = (float*)d_out;           // 32 floats: weights(16) + indices(16)
    float* plogit   = (float*)d_ws;            // 1024*64 floats = 256 KB

    fused_stream_kernel<<<BB * NCHUNK * 2, 256, 0, stream>>>(x, W, plogit);
    gate_kernel<<<BB, 256, 0, stream>>>(plogit, bb, out);
}